// Round 1
// baseline (208.435 us; speedup 1.0000x reference)
//
#include <hip/hip_runtime.h>
#include <stdint.h>

typedef __bf16 bf16x8 __attribute__((ext_vector_type(8)));
typedef float f32x4 __attribute__((ext_vector_type(4)));
typedef uint32_t u32x2 __attribute__((ext_vector_type(2)));
typedef uint32_t u32x4 __attribute__((ext_vector_type(4)));

#define MFMA16(a, b, c) __builtin_amdgcn_mfma_f32_16x16x32_bf16((a), (b), (c), 0, 0, 0)

#if __has_builtin(__builtin_amdgcn_exp2f)
#define EXP2F(x) __builtin_amdgcn_exp2f(x)
#else
#define EXP2F(x) exp2f(x)
#endif

__device__ __forceinline__ void gload16(const void* gsrc, void* ldst) {
  // async global->LDS, 16B per lane; LDS dest is wave-uniform base + lane*16
  __builtin_amdgcn_global_load_lds((__attribute__((address_space(1))) void*)gsrc,
                                   (__attribute__((address_space(3))) void*)ldst, 16, 0, 0);
}

__device__ __forceinline__ uint32_t pkbf(float a, float b) {
  uint16_t ua = __builtin_bit_cast(uint16_t, (__bf16)a);
  uint16_t ub = __builtin_bit_cast(uint16_t, (__bf16)b);
  return (uint32_t)ua | ((uint32_t)ub << 16);
}

// ---------------------------------------------------------------------------
// prep: x (4096x1024 f32) -> bf16;  W[K,N] f32 -> Wt[N,K] bf16  (x3 matrices)
// ---------------------------------------------------------------------------
__global__ __launch_bounds__(256) void prep_kernel(
    const float* __restrict__ x, const float* __restrict__ Wq,
    const float* __restrict__ Wk, const float* __restrict__ Wv,
    ushort* __restrict__ xb, ushort* __restrict__ wt) {
  int tid = blockIdx.x * 256 + threadIdx.x;
  if (tid < 524288) {  // x: 4M floats, 8 per thread
    const f32x4* xp = (const f32x4*)x;
    f32x4 a = xp[tid * 2], b = xp[tid * 2 + 1];
    u32x4 o;
    o[0] = pkbf(a[0], a[1]);
    o[1] = pkbf(a[2], a[3]);
    o[2] = pkbf(b[0], b[1]);
    o[3] = pkbf(b[2], b[3]);
    *(u32x4*)(xb + (size_t)tid * 8) = o;
  } else {
    int r = tid - 524288;        // 0..393215
    int mtx = r >> 17;           // 0..2
    int q = r & 131071;
    int n = q & 1023, kc = q >> 10;  // n fast -> coalesced reads
    const float* W = (mtx == 0) ? Wq : (mtx == 1) ? Wk : Wv;
    const float* src = W + (size_t)kc * 8 * 1024 + n;
    float v0 = src[0], v1 = src[1024], v2 = src[2048], v3 = src[3072];
    float v4 = src[4096], v5 = src[5120], v6 = src[6144], v7 = src[7168];
    u32x4 o;
    o[0] = pkbf(v0, v1);
    o[1] = pkbf(v2, v3);
    o[2] = pkbf(v4, v5);
    o[3] = pkbf(v6, v7);
    *(u32x4*)(wt + (size_t)mtx * 1048576 + (size_t)n * 1024 + kc * 8) = o;
  }
}

// ---------------------------------------------------------------------------
// gemm_qkv: y = x @ W + b   (A=xb [4096,1024] bf16, B=Wt [1024(n),1024(k)] bf16)
// z=0 -> Q [b,h,s,d], z=1 -> K [b,h,s,d], z=2 -> V^T [b,h,d,s]   (all bf16)
// 128x128 tile, BK=64, 4 waves (2x2), 4x4 frags of 16x16x32, dbuf LDS,
// global_load_lds w/ pre-swizzled source, XOR-swizzled ds_read_b128.
// ---------------------------------------------------------------------------
__global__ __launch_bounds__(256, 2) void gemm_qkv(
    const ushort* __restrict__ xb, const ushort* __restrict__ wt,
    const float* __restrict__ bq, const float* __restrict__ bk,
    const float* __restrict__ bv, ushort* __restrict__ Qb,
    ushort* __restrict__ Kb, ushort* __restrict__ Vt) {
  __shared__ ushort ash[2][128 * 64];
  __shared__ ushort bsh[2][128 * 64];
  const int tid = threadIdx.x;
  const int w = tid >> 6, l = tid & 63;
  const int lq = l & 15, g = l >> 4;
  const int z = blockIdx.z;
  const int m0 = blockIdx.x * 128, n0 = blockIdx.y * 128;
  const ushort* A = xb;
  const ushort* B = wt + (size_t)z * 1048576;
  const float* bias = (z == 0) ? bq : (z == 1) ? bk : bv;

  const int lr = l >> 3;
  const int scol = ((l & 7) * 8) ^ (lr * 8);  // swizzled source col (elements)
  const int wr = w >> 1, wc = w & 1;
  const int swz = (lq & 7) << 4;  // read-side XOR swizzle (bytes)

  f32x4 acc[4][4] = {};

  auto stage = [&](int nb, int t) {
    int k0 = t * 64;
#pragma unroll
    for (int i = 0; i < 4; ++i) {
      int row = w * 32 + i * 8;
      gload16(A + (size_t)(m0 + row + lr) * 1024 + k0 + scol, &ash[nb][row * 64]);
    }
#pragma unroll
    for (int i = 0; i < 4; ++i) {
      int row = w * 32 + i * 8;
      gload16(B + (size_t)(n0 + row + lr) * 1024 + k0 + scol, &bsh[nb][row * 64]);
    }
  };

  stage(0, 0);
  __syncthreads();
  int buf = 0;
  for (int t = 0; t < 16; ++t) {
    if (t < 15) stage(buf ^ 1, t + 1);
    bf16x8 af[4][2], bfr[4][2];
#pragma unroll
    for (int mi = 0; mi < 4; ++mi)
#pragma unroll
      for (int kk = 0; kk < 2; ++kk) {
        int row = wr * 64 + mi * 16 + lq;
        af[mi][kk] = *(const bf16x8*)((const char*)&ash[buf][0] + row * 128 +
                                      ((kk * 64 + g * 16) ^ swz));
      }
#pragma unroll
    for (int ni = 0; ni < 4; ++ni)
#pragma unroll
      for (int kk = 0; kk < 2; ++kk) {
        int row = wc * 64 + ni * 16 + lq;
        bfr[ni][kk] = *(const bf16x8*)((const char*)&bsh[buf][0] + row * 128 +
                                       ((kk * 64 + g * 16) ^ swz));
      }
#pragma unroll
    for (int mi = 0; mi < 4; ++mi)
#pragma unroll
      for (int ni = 0; ni < 4; ++ni) {
        acc[mi][ni] = MFMA16(af[mi][0], bfr[ni][0], acc[mi][ni]);
        acc[mi][ni] = MFMA16(af[mi][1], bfr[ni][1], acc[mi][ni]);
      }
    __syncthreads();
    buf ^= 1;
  }

  // epilogue: C row m = g*4+j (+16mi+64wr), col n = lq (+16ni+64wc)
#pragma unroll
  for (int ni = 0; ni < 4; ++ni) {
    int nn = n0 + wc * 64 + ni * 16 + lq;
    int h = nn >> 6, d = nn & 63;
    float bb = bias[nn];
#pragma unroll
    for (int mi = 0; mi < 4; ++mi) {
      int mbase = m0 + wr * 64 + mi * 16 + g * 4;
      if (z < 2) {
        ushort* dst = (z == 0) ? Qb : Kb;
#pragma unroll
        for (int j = 0; j < 4; ++j) {
          int mm = mbase + j;
          int b = mm >> 11, s = mm & 2047;
          float v = acc[mi][ni][j] + bb;
          dst[((size_t)(b * 16 + h) * 2048 + s) * 64 + d] =
              __builtin_bit_cast(uint16_t, (__bf16)v);
        }
      } else {
        int b = mbase >> 11, s0 = mbase & 2047;
        u32x2 pk;
        pk[0] = pkbf(acc[mi][ni][0] + bb, acc[mi][ni][1] + bb);
        pk[1] = pkbf(acc[mi][ni][2] + bb, acc[mi][ni][3] + bb);
        *(u32x2*)(Vt + ((size_t)(b * 16 + h) * 64 + d) * 2048 + s0) = pk;
      }
    }
  }
}

// ---------------------------------------------------------------------------
// attn: flash attention. grid (qtile=16, h=16, b=2), 256 thr (4 waves x 32 q).
// Swapped QK^T: S^T = mfma(Kfrag, Qfrag) -> lane holds col q=l&15, rows k.
// Softmax lane-local (in-lane 16 + shfl_xor 16/32). P -> swizzled per-wave LDS.
// PV^T: O^T = mfma(V^T frag, P^T frag) -> rescale/div need no shuffles.
// ---------------------------------------------------------------------------
__global__ __launch_bounds__(256, 2) void attn_kernel(
    const ushort* __restrict__ Qb, const ushort* __restrict__ Kb,
    const ushort* __restrict__ Vt, const int* __restrict__ mask,
    const int* __restrict__ invp, float* __restrict__ out) {
  __shared__ ushort ksh[2][64 * 64];
  __shared__ ushort vsh[2][64 * 64];
  __shared__ ushort psh[4][32 * 64];
  const int tid = threadIdx.x;
  const int w = tid >> 6, l = tid & 63;
  const int lq = l & 15, g = l >> 4;
  const int qt = blockIdx.x, h = blockIdx.y, b = blockIdx.z;
  const int bh = b * 16 + h;
  const ushort* Qp = Qb + ((size_t)bh * 2048 + qt * 128 + w * 32) * 64;
  const ushort* Kp = Kb + (size_t)bh * 2048 * 64;
  const ushort* Vp = Vt + (size_t)bh * 64 * 2048;
  const int* mp = mask + b * 2048;
  const float c = 1.44269504088896341f / (float)(*invp);  // log2(e)/inv_scale

  const int lr = l >> 3;
  const int scol = ((l & 7) * 8) ^ (lr * 8);
  const int swz = (lq & 7) << 4;

  // Q fragments (persistent): lane holds row q=lq(+16qf), d = kk*32+g*8..+7
  bf16x8 qf_[2][2];
#pragma unroll
  for (int qf = 0; qf < 2; ++qf)
#pragma unroll
    for (int kk = 0; kk < 2; ++kk)
      qf_[qf][kk] = *(const bf16x8*)(Qp + (qf * 16 + lq) * 64 + kk * 32 + g * 8);

  f32x4 acco[4][2] = {};  // O^T frags: row d = g*4+j (+16nd), col q = lq (+16qf)
  float m_[2] = {-__builtin_inff(), -__builtin_inff()};
  float l_[2] = {0.f, 0.f};

  auto stage = [&](int nb, int t) {
#pragma unroll
    for (int i = 0; i < 2; ++i) {
      int row = w * 16 + i * 8;
      gload16(Kp + (size_t)(t * 64 + row + lr) * 64 + scol, &ksh[nb][row * 64]);
      gload16(Vp + (size_t)(row + lr) * 2048 + t * 64 + scol, &vsh[nb][row * 64]);
    }
  };
  stage(0, 0);
  __syncthreads();
  int buf = 0;
  for (int t = 0; t < 32; ++t) {
    if (t < 31) stage(buf ^ 1, t + 1);
    // --- S^T = K * Q^T ---
    f32x4 sc[2][4];
    bf16x8 kf_[4][2];
#pragma unroll
    for (int kf = 0; kf < 4; ++kf)
#pragma unroll
      for (int kk = 0; kk < 2; ++kk) {
        int row = kf * 16 + lq;
        kf_[kf][kk] = *(const bf16x8*)((const char*)&ksh[buf][0] + row * 128 +
                                       ((kk * 64 + g * 16) ^ swz));
      }
#pragma unroll
    for (int qf = 0; qf < 2; ++qf)
#pragma unroll
      for (int kf = 0; kf < 4; ++kf) {
        f32x4 zz = {0.f, 0.f, 0.f, 0.f};
        zz = MFMA16(kf_[kf][0], qf_[qf][0], zz);
        sc[qf][kf] = MFMA16(kf_[kf][1], qf_[qf][1], zz);
      }
    // masks for k = t*64 + kf*16 + g*4 + j
    int4 mv[4];
#pragma unroll
    for (int kf = 0; kf < 4; ++kf)
      mv[kf] = *(const int4*)(mp + t * 64 + kf * 16 + g * 4);
    // --- online softmax (per qf; lane owns column q) ---
#pragma unroll
    for (int qf = 0; qf < 2; ++qf) {
      float mx = -__builtin_inff();
#pragma unroll
      for (int kf = 0; kf < 4; ++kf) {
        sc[qf][kf] *= c;
#pragma unroll
        for (int j = 0; j < 4; ++j) mx = fmaxf(mx, sc[qf][kf][j]);
      }
      mx = fmaxf(mx, __shfl_xor(mx, 16, 64));
      mx = fmaxf(mx, __shfl_xor(mx, 32, 64));
      float mnew = fmaxf(m_[qf], mx);
      float alpha = EXP2F(m_[qf] - mnew);
      m_[qf] = mnew;
      float ps = 0.f;
      int p = qf * 16 + lq;
      char* pbase = (char*)&psh[w][0] + p * 128;
#pragma unroll
      for (int kf = 0; kf < 4; ++kf) {
        float pv[4];
#pragma unroll
        for (int j = 0; j < 4; ++j) {
          float e = EXP2F(sc[qf][kf][j] - mnew);
          int mm = (j == 0) ? mv[kf].x : (j == 1) ? mv[kf].y : (j == 2) ? mv[kf].z : mv[kf].w;
          e = mm ? e : 0.f;
          pv[j] = e;
          ps += e;
        }
        u32x2 pk2;
        pk2[0] = pkbf(pv[0], pv[1]);
        pk2[1] = pkbf(pv[2], pv[3]);
        *(u32x2*)(pbase + ((kf * 32 + g * 8) ^ swz)) = pk2;
      }
      ps += __shfl_xor(ps, 16, 64);
      ps += __shfl_xor(ps, 32, 64);
      l_[qf] = l_[qf] * alpha + ps;
#pragma unroll
      for (int nd = 0; nd < 4; ++nd) acco[nd][qf] *= alpha;
    }
    // --- O^T += V^T * P^T ---
    bf16x8 pf[2][2], vf[4][2];
#pragma unroll
    for (int qf = 0; qf < 2; ++qf)
#pragma unroll
      for (int kc = 0; kc < 2; ++kc) {
        int p = qf * 16 + lq;
        pf[qf][kc] = *(const bf16x8*)((const char*)&psh[w][0] + p * 128 +
                                      ((kc * 64 + g * 16) ^ swz));
      }
#pragma unroll
    for (int nd = 0; nd < 4; ++nd)
#pragma unroll
      for (int kc = 0; kc < 2; ++kc) {
        int row = nd * 16 + lq;
        vf[nd][kc] = *(const bf16x8*)((const char*)&vsh[buf][0] + row * 128 +
                                      ((kc * 64 + g * 16) ^ swz));
      }
#pragma unroll
    for (int nd = 0; nd < 4; ++nd)
#pragma unroll
      for (int qf = 0; qf < 2; ++qf) {
        acco[nd][qf] = MFMA16(vf[nd][0], pf[qf][0], acco[nd][qf]);
        acco[nd][qf] = MFMA16(vf[nd][1], pf[qf][1], acco[nd][qf]);
      }
    __syncthreads();
    buf ^= 1;
  }
  // epilogue: out[b,h,q,d] = acco^T / l
#pragma unroll
  for (int qf = 0; qf < 2; ++qf) {
    float r = 1.0f / l_[qf];
    int qrow = qt * 128 + w * 32 + qf * 16 + lq;
#pragma unroll
    for (int nd = 0; nd < 4; ++nd) {
      f32x4 v = acco[nd][qf] * r;
      int d0 = nd * 16 + g * 4;
      *(f32x4*)(out + ((size_t)bh * 2048 + qrow) * 64 + d0) = v;
    }
  }
}

// ---------------------------------------------------------------------------
extern "C" void kernel_launch(void* const* d_in, const int* in_sizes, int n_in,
                              void* d_out, int out_size, void* d_ws,
                              size_t ws_size, hipStream_t stream) {
  (void)in_sizes; (void)n_in; (void)out_size; (void)ws_size;
  const float* x = (const float*)d_in[0];
  const int* mask = (const int*)d_in[1];
  const int* invp = (const int*)d_in[2];
  const float* Wq = (const float*)d_in[3];
  const float* bq = (const float*)d_in[4];
  const float* Wk = (const float*)d_in[5];
  const float* bk = (const float*)d_in[6];
  const float* Wv = (const float*)d_in[7];
  const float* bv = (const float*)d_in[8];

  ushort* xb = (ushort*)d_ws;          // 4194304 elems
  ushort* wt = xb + 4194304;           // 3*1048576 elems
  ushort* Qb = wt + 3145728;           // 4194304 elems
  ushort* Kb = Qb + 4194304;           // 4194304 elems
  ushort* Vt = Kb + 4194304;           // 4194304 elems (transposed [b,h,d,s])
  float* out = (float*)d_out;

  prep_kernel<<<3584, 256, 0, stream>>>(x, Wq, Wk, Wv, xb, wt);
  gemm_qkv<<<dim3(32, 8, 3), 256, 0, stream>>>(xb, wt, bq, bk, bv, Qb, Kb, Vt);
  attn_kernel<<<dim3(16, 16, 2), 256, 0, stream>>>(Qb, Kb, Vt, mask, invp, out);
}

// Round 2
// 198.499 us; speedup vs baseline: 1.0501x; 1.0501x over previous
//
#include <hip/hip_runtime.h>
#include <stdint.h>

typedef __bf16 bf16x8 __attribute__((ext_vector_type(8)));
typedef float f32x4 __attribute__((ext_vector_type(4)));
typedef uint32_t u32x2 __attribute__((ext_vector_type(2)));
typedef uint32_t u32x4 __attribute__((ext_vector_type(4)));

#define MFMA16(a, b, c) __builtin_amdgcn_mfma_f32_16x16x32_bf16((a), (b), (c), 0, 0, 0)

#if __has_builtin(__builtin_amdgcn_exp2f)
#define EXP2F(x) __builtin_amdgcn_exp2f(x)
#else
#define EXP2F(x) exp2f(x)
#endif

__device__ __forceinline__ void gload16(const void* gsrc, void* ldst) {
  __builtin_amdgcn_global_load_lds((__attribute__((address_space(1))) void*)gsrc,
                                   (__attribute__((address_space(3))) void*)ldst, 16, 0, 0);
}

__device__ __forceinline__ uint32_t pkbf(float a, float b) {
  uint16_t ua = __builtin_bit_cast(uint16_t, (__bf16)a);
  uint16_t ub = __builtin_bit_cast(uint16_t, (__bf16)b);
  return (uint32_t)ua | ((uint32_t)ub << 16);
}

// ---------------------------------------------------------------------------
// prep: x (4096x1024 f32) -> bf16;  W[K,N] f32 -> Wt[N,K] bf16  (x3 matrices)
// ---------------------------------------------------------------------------
__global__ __launch_bounds__(256) void prep_kernel(
    const float* __restrict__ x, const float* __restrict__ Wq,
    const float* __restrict__ Wk, const float* __restrict__ Wv,
    ushort* __restrict__ xb, ushort* __restrict__ wt) {
  int tid = blockIdx.x * 256 + threadIdx.x;
  if (tid < 524288) {  // x: 4M floats, 8 per thread
    const f32x4* xp = (const f32x4*)x;
    f32x4 a = xp[tid * 2], b = xp[tid * 2 + 1];
    u32x4 o;
    o[0] = pkbf(a[0], a[1]);
    o[1] = pkbf(a[2], a[3]);
    o[2] = pkbf(b[0], b[1]);
    o[3] = pkbf(b[2], b[3]);
    *(u32x4*)(xb + (size_t)tid * 8) = o;
  } else {
    int r = tid - 524288;        // 0..393215
    int mtx = r >> 17;           // 0..2
    int q = r & 131071;
    int n = q & 1023, kc = q >> 10;  // n fast -> coalesced reads
    const float* W = (mtx == 0) ? Wq : (mtx == 1) ? Wk : Wv;
    const float* src = W + (size_t)kc * 8 * 1024 + n;
    float v0 = src[0], v1 = src[1024], v2 = src[2048], v3 = src[3072];
    float v4 = src[4096], v5 = src[5120], v6 = src[6144], v7 = src[7168];
    u32x4 o;
    o[0] = pkbf(v0, v1);
    o[1] = pkbf(v2, v3);
    o[2] = pkbf(v4, v5);
    o[3] = pkbf(v6, v7);
    *(u32x4*)(wt + (size_t)mtx * 1048576 + (size_t)n * 1024 + kc * 8) = o;
  }
}

// ---------------------------------------------------------------------------
// gemm_qkv: y = x @ W + b. Fused over z via 1D grid 768 (32 m-tiles x 24 n).
// z=0 -> Q*(log2e/inv_scale) [b,h,s,d], z=1 -> K [b,h,s,d], z=2 -> V^T [b,h,d,s]
// 128x128 tile, BK=64, 4 waves, dbuf LDS, global_load_lds + XOR swizzle.
// XCD-aware block swizzle (768 % 8 == 0).
// ---------------------------------------------------------------------------
__global__ __launch_bounds__(256, 2) void gemm_qkv(
    const ushort* __restrict__ xb, const ushort* __restrict__ wt,
    const float* __restrict__ bq, const float* __restrict__ bk,
    const float* __restrict__ bv, const int* __restrict__ invp,
    ushort* __restrict__ Qb, ushort* __restrict__ Kb, ushort* __restrict__ Vt) {
  __shared__ ushort ash[2][128 * 64];
  __shared__ ushort bsh[2][128 * 64];
  const int tid = threadIdx.x;
  const int w = tid >> 6, l = tid & 63;
  const int lq = l & 15, g = l >> 4;

  // XCD swizzle: consecutive nf share the A m-panel within one XCD
  const int f = blockIdx.x;
  const int nf = (f & 7) * 96 + (f >> 3);
  const int bx = nf / 24, byy = nf % 24;
  const int z = byy >> 3;
  const int m0 = bx * 128, n0 = (byy & 7) * 128;

  const ushort* A = xb;
  const ushort* B = wt + (size_t)z * 1048576;
  const float* bias = (z == 0) ? bq : (z == 1) ? bk : bv;
  const float qs = 1.44269504088896341f / (float)(invp[0]);

  const int lr = l >> 3;
  const int scol = ((l & 7) * 8) ^ (lr * 8);  // swizzled source col (elements)
  const int wr = w >> 1, wc = w & 1;
  const int swz = (lq & 7) << 4;  // read-side XOR swizzle (bytes)

  f32x4 acc[4][4] = {};

  auto stage = [&](int nb, int t) {
    int k0 = t * 64;
#pragma unroll
    for (int i = 0; i < 4; ++i) {
      int row = w * 32 + i * 8;
      gload16(A + (size_t)(m0 + row + lr) * 1024 + k0 + scol, &ash[nb][row * 64]);
    }
#pragma unroll
    for (int i = 0; i < 4; ++i) {
      int row = w * 32 + i * 8;
      gload16(B + (size_t)(n0 + row + lr) * 1024 + k0 + scol, &bsh[nb][row * 64]);
    }
  };

  stage(0, 0);
  __syncthreads();
  int buf = 0;
  for (int t = 0; t < 16; ++t) {
    if (t < 15) stage(buf ^ 1, t + 1);
    bf16x8 af[4][2], bfr[4][2];
#pragma unroll
    for (int mi = 0; mi < 4; ++mi)
#pragma unroll
      for (int kk = 0; kk < 2; ++kk) {
        int row = wr * 64 + mi * 16 + lq;
        af[mi][kk] = *(const bf16x8*)((const char*)&ash[buf][0] + row * 128 +
                                      ((kk * 64 + g * 16) ^ swz));
      }
#pragma unroll
    for (int ni = 0; ni < 4; ++ni)
#pragma unroll
      for (int kk = 0; kk < 2; ++kk) {
        int row = wc * 64 + ni * 16 + lq;
        bfr[ni][kk] = *(const bf16x8*)((const char*)&bsh[buf][0] + row * 128 +
                                       ((kk * 64 + g * 16) ^ swz));
      }
#pragma unroll
    for (int mi = 0; mi < 4; ++mi)
#pragma unroll
      for (int ni = 0; ni < 4; ++ni) {
        acc[mi][ni] = MFMA16(af[mi][0], bfr[ni][0], acc[mi][ni]);
        acc[mi][ni] = MFMA16(af[mi][1], bfr[ni][1], acc[mi][ni]);
      }
    __syncthreads();
    buf ^= 1;
  }

  // epilogue: C row m = g*4+j (+16mi+64wr), col n = lq (+16ni+64wc)
#pragma unroll
  for (int ni = 0; ni < 4; ++ni) {
    int nn = n0 + wc * 64 + ni * 16 + lq;
    int h = nn >> 6, d = nn & 63;
    float bb = bias[nn];
#pragma unroll
    for (int mi = 0; mi < 4; ++mi) {
      int mbase = m0 + wr * 64 + mi * 16 + g * 4;
      if (z < 2) {
        ushort* dst = (z == 0) ? Qb : Kb;
#pragma unroll
        for (int j = 0; j < 4; ++j) {
          int mm = mbase + j;
          int b = mm >> 11, s = mm & 2047;
          float v = acc[mi][ni][j] + bb;
          if (z == 0) v *= qs;  // fold log2e/inv_scale into Q
          dst[((size_t)(b * 16 + h) * 2048 + s) * 64 + d] =
              __builtin_bit_cast(uint16_t, (__bf16)v);
        }
      } else {
        int b = mbase >> 11, s0 = mbase & 2047;
        u32x2 pk;
        pk[0] = pkbf(acc[mi][ni][0] + bb, acc[mi][ni][1] + bb);
        pk[1] = pkbf(acc[mi][ni][2] + bb, acc[mi][ni][3] + bb);
        *(u32x2*)(Vt + ((size_t)(b * 16 + h) * 64 + d) * 2048 + s0) = pk;
      }
    }
  }
}

// ---------------------------------------------------------------------------
// attn: flash attention. 1024 blocks (32 qtiles x 32 bh), 256 thr (4 waves),
// 64 q-rows/block (16 per wave). LDS 40KB -> 4 blocks/CU, 16 waves/CU.
// Swapped QK^T (lane-local softmax), defer-max (THR=8 in log2 domain),
// setprio around MFMA, XCD swizzle for K/V L2 locality.
// ---------------------------------------------------------------------------
__global__ __launch_bounds__(256, 4) void attn_kernel(
    const ushort* __restrict__ Qb, const ushort* __restrict__ Kb,
    const ushort* __restrict__ Vt, const int* __restrict__ mask,
    float* __restrict__ out) {
  __shared__ ushort ksh[2][64 * 64];
  __shared__ ushort vsh[2][64 * 64];
  __shared__ ushort psh[4][16 * 64];
  const int tid = threadIdx.x;
  const int w = tid >> 6, l = tid & 63;
  const int lq = l & 15, g = l >> 4;

  // XCD swizzle: each XCD gets 4 consecutive bh (2MB K/V resident in its L2)
  const int f = blockIdx.x;
  const int nf = ((f & 7) << 7) + (f >> 3);  // 1024 blocks, bijective
  const int qt = nf & 31, bh = nf >> 5;
  const int b = bh >> 4;

  const ushort* Qp = Qb + ((size_t)bh * 2048 + qt * 64 + w * 16) * 64;
  const ushort* Kp = Kb + (size_t)bh * 2048 * 64;
  const ushort* Vp = Vt + (size_t)bh * 64 * 2048;
  const int* mp = mask + b * 2048;

  const int lr = l >> 3;
  const int scol = ((l & 7) * 8) ^ (lr * 8);
  const int swz = (lq & 7) << 4;

  // Q fragments (persistent): lane holds row q=lq, d = kk*32+g*8..+7
  bf16x8 qf_[2];
#pragma unroll
  for (int kk = 0; kk < 2; ++kk)
    qf_[kk] = *(const bf16x8*)(Qp + lq * 64 + kk * 32 + g * 8);

  f32x4 acco[4] = {};  // O^T frags: row d = g*4+j (+16nd), col q = lq
  float m_ = -__builtin_inff();
  float l_ = 0.f;

  auto stage = [&](int nb, int t) {
#pragma unroll
    for (int i = 0; i < 2; ++i) {
      int row = w * 16 + i * 8;
      gload16(Kp + (size_t)(t * 64 + row + lr) * 64 + scol, &ksh[nb][row * 64]);
      gload16(Vp + (size_t)(row + lr) * 2048 + t * 64 + scol, &vsh[nb][row * 64]);
    }
  };
  stage(0, 0);
  __syncthreads();
  int buf = 0;
  for (int t = 0; t < 32; ++t) {
    if (t < 31) stage(buf ^ 1, t + 1);
    // --- S^T = K * Q^T (already includes log2e/inv_scale via Q) ---
    bf16x8 kf_[4][2];
#pragma unroll
    for (int kf = 0; kf < 4; ++kf)
#pragma unroll
      for (int kk = 0; kk < 2; ++kk) {
        int row = kf * 16 + lq;
        kf_[kf][kk] = *(const bf16x8*)((const char*)&ksh[buf][0] + row * 128 +
                                       ((kk * 64 + g * 16) ^ swz));
      }
    f32x4 sc[4];
    __builtin_amdgcn_s_setprio(1);
#pragma unroll
    for (int kf = 0; kf < 4; ++kf) {
      f32x4 zz = {0.f, 0.f, 0.f, 0.f};
      zz = MFMA16(kf_[kf][0], qf_[0], zz);
      sc[kf] = MFMA16(kf_[kf][1], qf_[1], zz);
    }
    __builtin_amdgcn_s_setprio(0);
    // masks for k = t*64 + kf*16 + g*4 + j
    int4 mv[4];
#pragma unroll
    for (int kf = 0; kf < 4; ++kf)
      mv[kf] = *(const int4*)(mp + t * 64 + kf * 16 + g * 4);
    // --- online softmax (lane owns column q = lq) ---
    float mx = -__builtin_inff();
#pragma unroll
    for (int kf = 0; kf < 4; ++kf)
#pragma unroll
      for (int j = 0; j < 4; ++j) mx = fmaxf(mx, sc[kf][j]);
    mx = fmaxf(mx, __shfl_xor(mx, 16, 64));
    mx = fmaxf(mx, __shfl_xor(mx, 32, 64));
    // defer-max: only rescale when tile max grew by >8 (2^8 headroom in bf16 P)
    if (!__all(mx - m_ <= 8.f)) {
      float mnew = fmaxf(m_, mx);
      float alpha = EXP2F(m_ - mnew);
      m_ = mnew;
      l_ *= alpha;
#pragma unroll
      for (int nd = 0; nd < 4; ++nd) acco[nd] *= alpha;
    }
    float ps = 0.f;
    char* pbase = (char*)&psh[w][0] + lq * 128;
#pragma unroll
    for (int kf = 0; kf < 4; ++kf) {
      float pv[4];
#pragma unroll
      for (int j = 0; j < 4; ++j) {
        float e = EXP2F(sc[kf][j] - m_);
        int mm = (j == 0) ? mv[kf].x : (j == 1) ? mv[kf].y : (j == 2) ? mv[kf].z : mv[kf].w;
        e = mm ? e : 0.f;
        pv[j] = e;
        ps += e;
      }
      u32x2 pk2;
      pk2[0] = pkbf(pv[0], pv[1]);
      pk2[1] = pkbf(pv[2], pv[3]);
      *(u32x2*)(pbase + ((kf * 32 + g * 8) ^ swz)) = pk2;
    }
    ps += __shfl_xor(ps, 16, 64);
    ps += __shfl_xor(ps, 32, 64);
    l_ += ps;
    // --- O^T += V^T * P^T ---
    bf16x8 pf[2], vf[4][2];
#pragma unroll
    for (int kc = 0; kc < 2; ++kc)
      pf[kc] = *(const bf16x8*)((const char*)&psh[w][0] + lq * 128 +
                                ((kc * 64 + g * 16) ^ swz));
#pragma unroll
    for (int nd = 0; nd < 4; ++nd)
#pragma unroll
      for (int kc = 0; kc < 2; ++kc) {
        int row = nd * 16 + lq;
        vf[nd][kc] = *(const bf16x8*)((const char*)&vsh[buf][0] + row * 128 +
                                      ((kc * 64 + g * 16) ^ swz));
      }
    __builtin_amdgcn_s_setprio(1);
#pragma unroll
    for (int nd = 0; nd < 4; ++nd) {
      acco[nd] = MFMA16(vf[nd][0], pf[0], acco[nd]);
      acco[nd] = MFMA16(vf[nd][1], pf[1], acco[nd]);
    }
    __builtin_amdgcn_s_setprio(0);
    __syncthreads();
    buf ^= 1;
  }
  // epilogue: out[b,h,q,d] = acco^T / l
  float r = 1.0f / l_;
  int qrow = qt * 64 + w * 16 + lq;
#pragma unroll
  for (int nd = 0; nd < 4; ++nd) {
    f32x4 v = acco[nd] * r;
    int d0 = nd * 16 + g * 4;
    *(f32x4*)(out + ((size_t)bh * 2048 + qrow) * 64 + d0) = v;
  }
}

// ---------------------------------------------------------------------------
extern "C" void kernel_launch(void* const* d_in, const int* in_sizes, int n_in,
                              void* d_out, int out_size, void* d_ws,
                              size_t ws_size, hipStream_t stream) {
  (void)in_sizes; (void)n_in; (void)out_size; (void)ws_size;
  const float* x = (const float*)d_in[0];
  const int* mask = (const int*)d_in[1];
  const int* invp = (const int*)d_in[2];
  const float* Wq = (const float*)d_in[3];
  const float* bq = (const float*)d_in[4];
  const float* Wk = (const float*)d_in[5];
  const float* bk = (const float*)d_in[6];
  const float* Wv = (const float*)d_in[7];
  const float* bv = (const float*)d_in[8];

  ushort* xb = (ushort*)d_ws;          // 4194304 elems
  ushort* wt = xb + 4194304;           // 3*1048576 elems
  ushort* Qb = wt + 3145728;           // 4194304 elems (pre-scaled by log2e/inv)
  ushort* Kb = Qb + 4194304;           // 4194304 elems
  ushort* Vt = Kb + 4194304;           // 4194304 elems (transposed [b,h,d,s])
  float* out = (float*)d_out;

  prep_kernel<<<3584, 256, 0, stream>>>(x, Wq, Wk, Wv, xb, wt);
  gemm_qkv<<<768, 256, 0, stream>>>(xb, wt, bq, bk, bv, invp, Qb, Kb, Vt);
  attn_kernel<<<1024, 256, 0, stream>>>(Qb, Kb, Vt, mask, out);
}